// Round 15
// baseline (112.605 us; speedup 1.0000x reference)
//
#include <hip/hip_runtime.h>
#include <hip/hip_bf16.h>

#define NNODE 100000
#define CIN   64
#define CHID  64
#define NREL  8
#define NGRP  6250     // NNODE / 16

typedef __attribute__((ext_vector_type(8))) short bf16x8;
typedef __attribute__((ext_vector_type(4))) float f32x4;
typedef __attribute__((ext_vector_type(2))) float f32x2;
typedef unsigned long long u64;

__device__ __forceinline__ unsigned short f2bf(float f) {
    __hip_bfloat16 h = __float2bfloat16(f);
    return __builtin_bit_cast(unsigned short, h);
}
__device__ __forceinline__ float bf2f(unsigned short u) {
    unsigned int v = ((unsigned int)u) << 16;
    return __builtin_bit_cast(float, v);
}
template <int SEL>
__device__ __forceinline__ float f8tof(unsigned int w) {
    return __builtin_amdgcn_cvt_f32_fp8(w, SEL);   // OCP e4m3 on gfx950
}

// ---- prep: x (f32) -> xb (fp8 e4m3), 4 elems/thread ----
__global__ void k_prep_x(const float* __restrict__ x, unsigned int* __restrict__ xb) {
    int i = blockIdx.x * 256 + threadIdx.x;
    if (i >= NNODE * CIN / 4) return;
    float4 v = *reinterpret_cast<const float4*>(x + (size_t)i * 4);
    int p = __builtin_amdgcn_cvt_pk_fp8_f32(v.x, v.y, 0, false);
    p = __builtin_amdgcn_cvt_pk_fp8_f32(v.z, v.w, p, true);
    xb[i] = (unsigned int)p;
}

// ---- prep: per-node counting sort of edges by type (deg==16 fast case) ----
__global__ void k_sort(const int* __restrict__ ptr, const int* __restrict__ idx,
                       const int* __restrict__ et, int* __restrict__ sidx,
                       u64* __restrict__ typ4) {
    int node = blockIdx.x * 256 + threadIdx.x;
    if (node >= NNODE) return;
    int eb = ptr[node], en = ptr[node + 1];
    if (en - eb != 16) { typ4[node] = 0; return; }
    u64 cnt = 0;
#pragma unroll
    for (int ee = 0; ee < 16; ++ee)
        cnt += 1ull << (8 * et[eb + ee]);
    u64 pre = cnt * 0x0101010101010100ull;   // exclusive byte prefix sums
    u64 occ = 0, tp = 0;
#pragma unroll
    for (int ee = 0; ee < 16; ++ee) {
        int te = et[eb + ee];
        int sh = te * 8;
        int pos = (int)((pre >> sh) & 0xFF) + (int)((occ >> sh) & 0xFF);
        occ += 1ull << sh;
        sidx[eb + pos] = idx[eb + ee];
        tp |= (u64)te << (4 * pos);
    }
    typ4[node] = tp;
}

// ---- prep: W (f32 [8][64][64]) -> B-fragment-ordered bf16, flat k = r*64 + ki ----
__global__ void k_prep_w(const float* __restrict__ W, unsigned short* __restrict__ wf) {
    int tid = blockIdx.x * 256 + threadIdx.x;
    if (tid >= 64 * 64) return;
    int tile = tid >> 6, lane = tid & 63;
    int kt = tile >> 2, nt = tile & 3;
    int kbase = kt * 32 + (lane >> 4) * 8;
    int col = nt * 16 + (lane & 15);
    unsigned short v[8];
#pragma unroll
    for (int j = 0; j < 8; ++j)
        v[j] = f2bf(W[(kbase + j) * 64 + col]);
    ushort4* dst = reinterpret_cast<ushort4*>(wf + (size_t)tid * 8);
    ushort4 lo, hi;
    lo.x = v[0]; lo.y = v[1]; lo.z = v[2]; lo.w = v[3];
    hi.x = v[4]; hi.y = v[5]; hi.z = v[6]; hi.w = v[7];
    dst[0] = lo; dst[1] = hi;
}

// ---- main: R13 structure (best passing config) ----
__launch_bounds__(256, 8)
__global__ void k_main(const unsigned char* __restrict__ xb,
                       const bf16x8* __restrict__ wf,
                       const int* __restrict__ ptr,
                       const int* __restrict__ sidx,
                       const u64* __restrict__ typ4,
                       const int* __restrict__ idx,
                       const int* __restrict__ et,
                       const int* __restrict__ hmap,
                       const float* __restrict__ hbuf,
                       float* __restrict__ out) {
    __shared__ __align__(16) unsigned short S[8192];   // 16 rows x 512 k, 16 KB
    __shared__ __align__(16) int VS[4][64];            // per-wave sorted-source strip

    int wave = __builtin_amdgcn_readfirstlane((int)(threadIdx.x >> 6));
    int lane = threadIdx.x & 63;
    int n0 = blockIdx.x * 16;
    int nbase = n0 + wave * 4;
    char* sb = reinterpret_cast<char*>(&S[0]);

    {
        f32x4 z = {0.f, 0.f, 0.f, 0.f};
        f32x4* sz = reinterpret_cast<f32x4*>(sb);
        sz[threadIdx.x]       = z;
        sz[threadIdx.x + 256] = z;
        sz[threadIdx.x + 512] = z;
        sz[threadIdx.x + 768] = z;
    }
    __syncthreads();

    int ebX = nbase * 16;
    int eb0 = ptr[nbase + 0], eb1 = ptr[nbase + 1], eb2 = ptr[nbase + 2],
        eb3 = ptr[nbase + 3], eb4 = ptr[nbase + 4];
    bool fixed16 = (eb0 == ebX) && (eb1 == ebX + 16) && (eb2 == ebX + 32) &&
                   (eb3 == ebX + 48) && (eb4 == ebX + 64);

    if (fixed16) {
        VS[wave][lane] = sidx[ebX + lane];

        u64 tp0 = typ4[nbase + 0], tp1 = typ4[nbase + 1],
            tp2 = typ4[nbase + 2], tp3 = typ4[nbase + 3];

        int g = lane >> 4;
        u64 tpg = (g == 0) ? tp0 : ((g == 1) ? tp1 : ((g == 2) ? tp2 : tp3));
        int row = wave * 4 + g;
        unsigned int rowxor  = ((unsigned int)(row & 7)) << 4;
        unsigned int rowbase = (unsigned int)row * 1024u;
        unsigned int chb     = (unsigned int)(lane & 15) * 8u;
        unsigned int choff   = (unsigned int)(lane & 15) * 4u;

        const int* vsp = &VS[wave][g * 16];
        int4 q0 = *reinterpret_cast<const int4*>(vsp);
        int4 q1 = *reinterpret_cast<const int4*>(vsp + 4);
        int4 q2 = *reinterpret_cast<const int4*>(vsp + 8);
        int4 q3 = *reinterpret_cast<const int4*>(vsp + 12);

#define LD(s) (*reinterpret_cast<const unsigned int*>( \
                   xb + (size_t)(((unsigned int)(s)) * 64u + choff)))
        unsigned int d0  = LD(q0.x), d1  = LD(q0.y), d2  = LD(q0.z), d3  = LD(q0.w);
        unsigned int d4  = LD(q1.x), d5  = LD(q1.y), d6  = LD(q1.z), d7  = LD(q1.w);
        unsigned int d8  = LD(q2.x), d9  = LD(q2.y), d10 = LD(q2.z), d11 = LD(q2.w);
        unsigned int d12 = LD(q3.x), d13 = LD(q3.y), d14 = LD(q3.z), d15 = LD(q3.w);
#undef LD

        float s0 = 0.f, s1 = 0.f, s2 = 0.f, s3 = 0.f;

#define STEP(ee, dd)                                                          \
        {                                                                     \
            f32x2 plo = __builtin_amdgcn_cvt_pk_f32_fp8((int)(dd), false);    \
            f32x2 phi = __builtin_amdgcn_cvt_pk_f32_fp8((int)(dd), true);     \
            s0 += plo[0]; s1 += plo[1]; s2 += phi[0]; s3 += phi[1];           \
            int tcur = (int)((tpg >> ((4 * (ee)) & 63)) & 0xF);               \
            int tnxt = ((ee) == 15) ? 16                                      \
                                    : (int)((tpg >> ((4 * (ee) + 4) & 63)) & 0xF); \
            if (tcur != tnxt) {                                               \
                unsigned int lo = (unsigned int)f2bf(s0)                      \
                                | ((unsigned int)f2bf(s1) << 16);             \
                unsigned int hi = (unsigned int)f2bf(s2)                      \
                                | ((unsigned int)f2bf(s3) << 16);             \
                unsigned int byte = (rowbase + (unsigned int)tcur * 128u + chb) \
                                    ^ rowxor;                                 \
                uint2 pk; pk.x = lo; pk.y = hi;                               \
                *reinterpret_cast<uint2*>(sb + byte) = pk;                    \
                s0 = 0.f; s1 = 0.f; s2 = 0.f; s3 = 0.f;                       \
            }                                                                 \
        }

        STEP(0, d0);   STEP(1, d1);   STEP(2, d2);   STEP(3, d3);
        STEP(4, d4);   STEP(5, d5);   STEP(6, d6);   STEP(7, d7);
        STEP(8, d8);   STEP(9, d9);   STEP(10, d10); STEP(11, d11);
        STEP(12, d12); STEP(13, d13); STEP(14, d14); STEP(15, d15);
#undef STEP
    } else {
        int l16 = lane & 15;
        int ebs[5] = {eb0, eb1, eb2, eb3, eb4};
        for (int nn = 0; nn < 4; ++nn) {
            int eb = ebs[nn], en = ebs[nn + 1];
            float s0=0.f,s1=0.f,s2=0.f,s3=0.f,s4=0.f,s5=0.f,s6=0.f,s7=0.f;
            for (int e = eb; e < en; e += 16) {
                int m = en - e; if (m > 16) m = 16;
                int vi = 0, vt = 0;
                if (l16 < m) { vi = idx[e + l16]; vt = et[e + l16]; }
                for (int ee = 0; ee < m; ++ee) {
                    int src = __builtin_amdgcn_readlane(vi, ee);
                    int t   = __builtin_amdgcn_readlane(vt, ee);
                    float v = f8tof<0>((unsigned int)xb[(size_t)(unsigned)src * 64 + lane]);
                    if      (t == 0) s0 += v;
                    else if (t == 1) s1 += v;
                    else if (t == 2) s2 += v;
                    else if (t == 3) s3 += v;
                    else if (t == 4) s4 += v;
                    else if (t == 5) s5 += v;
                    else if (t == 6) s6 += v;
                    else             s7 += v;
                }
            }
            int row = wave * 4 + nn;
            unsigned int vlx = ((unsigned int)lane * 2u)
                               ^ (((unsigned int)(row & 7)) << 4);
            unsigned int rb = (unsigned int)row * 1024u;
            float sv[8] = {s0,s1,s2,s3,s4,s5,s6,s7};
#pragma unroll
            for (int r = 0; r < 8; ++r) {
                unsigned int byte = rb + (unsigned int)r * 128u + vlx;
                *reinterpret_cast<unsigned short*>(sb + byte) = f2bf(sv[r]);
            }
        }
    }
    __syncthreads();

    int nt = wave;
    f32x4 acc = {0.f,0.f,0.f,0.f};
    unsigned int arow  = (unsigned int)(lane & 15);
    unsigned int abase = arow * 1024u + (unsigned int)((lane >> 4) * 16);
    unsigned int axor  = (arow & 7u) << 4;
#pragma unroll 4
    for (int kt = 0; kt < 16; ++kt) {
        unsigned int abyte = (abase + (unsigned int)kt * 64u) ^ axor;
        bf16x8 a = *reinterpret_cast<const bf16x8*>(sb + abyte);
        bf16x8 b = wf[(kt * 4 + nt) * 64 + lane];
        acc = __builtin_amdgcn_mfma_f32_16x16x32_bf16(a, b, acc, 0, 0, 0);
    }

    int col   = nt * 16 + (lane & 15);
    int rquad = (lane >> 4) * 4;
#pragma unroll
    for (int j = 0; j < 4; ++j) {
        int node = n0 + rquad + j;
        float invd = 1.0f / (float)(ptr[node + 1] - ptr[node]);
        float v = acc[j] * invd;
        if (hmap[node] != -1) v = hbuf[node * 64 + col];
        out[node * 64 + col] = v;
        out[NNODE * 64 + node * 64 + col] = v;
    }
}

// ---- DIAGNOSTIC (writes only to ws scratch): identical fast-path pipeline,
// but gather sources masked into a 3.2MB window (src>>1) that FITS a 4MB
// per-XCD L2. Grid = 2*NGRP so it tops the rocprof table.
//   dur ~2x k_main  => L2-miss-capacity theory dead
//   dur ~1x k_main  => confirmed -> channel-split next round
__launch_bounds__(256, 8)
__global__ void k_abl(const unsigned char* __restrict__ xb,
                      const bf16x8* __restrict__ wf,
                      const int* __restrict__ ptr,
                      const int* __restrict__ sidx,
                      const u64* __restrict__ typ4,
                      float* __restrict__ scratch) {
    __shared__ __align__(16) unsigned short S[8192];
    __shared__ __align__(16) int VS[4][64];

    int wave = __builtin_amdgcn_readfirstlane((int)(threadIdx.x >> 6));
    int lane = threadIdx.x & 63;
    int group = blockIdx.x % NGRP;
    int nbase = group * 16 + wave * 4;
    char* sb = reinterpret_cast<char*>(&S[0]);

    {
        f32x4 z = {0.f, 0.f, 0.f, 0.f};
        f32x4* sz = reinterpret_cast<f32x4*>(sb);
        sz[threadIdx.x]       = z;
        sz[threadIdx.x + 256] = z;
        sz[threadIdx.x + 512] = z;
        sz[threadIdx.x + 768] = z;
    }
    __syncthreads();

    int ebX = nbase * 16;
    int eb0 = ptr[nbase + 0], eb4 = ptr[nbase + 4];
    bool fixed16 = (eb0 == ebX) && (eb4 == ebX + 64);

    if (fixed16) {
        VS[wave][lane] = sidx[ebX + lane];
        u64 tp0 = typ4[nbase + 0], tp1 = typ4[nbase + 1],
            tp2 = typ4[nbase + 2], tp3 = typ4[nbase + 3];
        int g = lane >> 4;
        u64 tpg = (g == 0) ? tp0 : ((g == 1) ? tp1 : ((g == 2) ? tp2 : tp3));
        int row = wave * 4 + g;
        unsigned int rowxor  = ((unsigned int)(row & 7)) << 4;
        unsigned int rowbase = (unsigned int)row * 1024u;
        unsigned int chb     = (unsigned int)(lane & 15) * 8u;
        unsigned int choff   = (unsigned int)(lane & 15) * 4u;

        const int* vsp = &VS[wave][g * 16];
        int4 q0 = *reinterpret_cast<const int4*>(vsp);
        int4 q1 = *reinterpret_cast<const int4*>(vsp + 4);
        int4 q2 = *reinterpret_cast<const int4*>(vsp + 8);
        int4 q3 = *reinterpret_cast<const int4*>(vsp + 12);

        // 3.2MB-window gather: src>>1 keeps the divergent pattern, halves range
#define LD(s) (*reinterpret_cast<const unsigned int*>( \
                   xb + (size_t)(((((unsigned int)(s)) >> 1) * 64u) + choff)))
        unsigned int d0  = LD(q0.x), d1  = LD(q0.y), d2  = LD(q0.z), d3  = LD(q0.w);
        unsigned int d4  = LD(q1.x), d5  = LD(q1.y), d6  = LD(q1.z), d7  = LD(q1.w);
        unsigned int d8  = LD(q2.x), d9  = LD(q2.y), d10 = LD(q2.z), d11 = LD(q2.w);
        unsigned int d12 = LD(q3.x), d13 = LD(q3.y), d14 = LD(q3.z), d15 = LD(q3.w);
#undef LD

        float s0 = 0.f, s1 = 0.f, s2 = 0.f, s3 = 0.f;
#define STEP(ee, dd)                                                          \
        {                                                                     \
            f32x2 plo = __builtin_amdgcn_cvt_pk_f32_fp8((int)(dd), false);    \
            f32x2 phi = __builtin_amdgcn_cvt_pk_f32_fp8((int)(dd), true);     \
            s0 += plo[0]; s1 += plo[1]; s2 += phi[0]; s3 += phi[1];           \
            int tcur = (int)((tpg >> ((4 * (ee)) & 63)) & 0xF);               \
            int tnxt = ((ee) == 15) ? 16                                      \
                                    : (int)((tpg >> ((4 * (ee) + 4) & 63)) & 0xF); \
            if (tcur != tnxt) {                                               \
                unsigned int lo = (unsigned int)f2bf(s0)                      \
                                | ((unsigned int)f2bf(s1) << 16);             \
                unsigned int hi = (unsigned int)f2bf(s2)                      \
                                | ((unsigned int)f2bf(s3) << 16);             \
                unsigned int byte = (rowbase + (unsigned int)tcur * 128u + chb) \
                                    ^ rowxor;                                 \
                uint2 pk; pk.x = lo; pk.y = hi;                               \
                *reinterpret_cast<uint2*>(sb + byte) = pk;                    \
                s0 = 0.f; s1 = 0.f; s2 = 0.f; s3 = 0.f;                       \
            }                                                                 \
        }
        STEP(0, d0);   STEP(1, d1);   STEP(2, d2);   STEP(3, d3);
        STEP(4, d4);   STEP(5, d5);   STEP(6, d6);   STEP(7, d7);
        STEP(8, d8);   STEP(9, d9);   STEP(10, d10); STEP(11, d11);
        STEP(12, d12); STEP(13, d13); STEP(14, d14); STEP(15, d15);
#undef STEP
    }
    __syncthreads();

    int nt = wave;
    f32x4 acc = {0.f,0.f,0.f,0.f};
    unsigned int arow  = (unsigned int)(lane & 15);
    unsigned int abase = arow * 1024u + (unsigned int)((lane >> 4) * 16);
    unsigned int axor  = (arow & 7u) << 4;
#pragma unroll 4
    for (int kt = 0; kt < 16; ++kt) {
        unsigned int abyte = (abase + (unsigned int)kt * 64u) ^ axor;
        bf16x8 a = *reinterpret_cast<const bf16x8*>(sb + abyte);
        bf16x8 b = wf[(kt * 4 + nt) * 64 + lane];
        acc = __builtin_amdgcn_mfma_f32_16x16x32_bf16(a, b, acc, 0, 0, 0);
    }
    scratch[(size_t)blockIdx.x * 256 + threadIdx.x] = acc[0] + acc[1] + acc[2] + acc[3];
}

extern "C" void kernel_launch(void* const* d_in, const int* in_sizes, int n_in,
                              void* d_out, int out_size, void* d_ws, size_t ws_size,
                              hipStream_t stream) {
    (void)in_sizes; (void)n_in; (void)out_size; (void)ws_size;
    const float* x    = (const float*)d_in[0];
    const float* W    = (const float*)d_in[1];
    const int*   ptr  = (const int*)d_in[2];
    const int*   idx  = (const int*)d_in[3];
    const int*   et   = (const int*)d_in[4];
    const int*   hmap = (const int*)d_in[6];
    const float* hbuf = (const float*)d_in[7];
    float* out = (float*)d_out;

    // workspace: xb(fp8) 6.4MB | wf 64KB | sidx 6.4MB | typ4 800KB | abl-scratch 12.8MB
    char* w = (char*)d_ws;
    unsigned char*  xb  = (unsigned char*)w;                   //  6,400,000 B
    unsigned short* wfu = (unsigned short*)(w + 6400000);      //     65,536 B
    int*            sidx= (int*)(w + 6465536);                 //  6,400,000 B
    u64*            tp4 = (u64*)(w + 12865536);                //    800,000 B
    float*          scr = (float*)(w + 13665536);              // 12,800,000 B

    k_prep_x<<<dim3(6250), dim3(256), 0, stream>>>(x, (unsigned int*)xb);
    k_sort<<<dim3((NNODE + 255) / 256), dim3(256), 0, stream>>>(ptr, idx, et, sidx, tp4);
    k_prep_w<<<dim3(16), dim3(256), 0, stream>>>(W, wfu);
    k_main<<<dim3(NGRP), dim3(256), 0, stream>>>(
        xb, (const bf16x8*)wfu, ptr, sidx, tp4, idx, et, hmap, hbuf, out);
    // diagnostic (scratch-only, after real output is complete)
    k_abl<<<dim3(2 * NGRP), dim3(256), 0, stream>>>(
        xb, (const bf16x8*)wfu, ptr, sidx, tp4, scr);
}

// Round 16
// 63.548 us; speedup vs baseline: 1.7720x; 1.7720x over previous
//
#include <hip/hip_runtime.h>
#include <hip/hip_bf16.h>

#define NNODE 100000
#define CIN   64
#define CHID  64
#define NREL  8
#define NGRP  6250     // NNODE / 16

typedef __attribute__((ext_vector_type(8))) short bf16x8;
typedef __attribute__((ext_vector_type(4))) float f32x4;
typedef __attribute__((ext_vector_type(2))) float f32x2;
typedef unsigned long long u64;

__device__ __forceinline__ unsigned short f2bf(float f) {
    __hip_bfloat16 h = __float2bfloat16(f);
    return __builtin_bit_cast(unsigned short, h);
}
template <int SEL>
__device__ __forceinline__ float f8tof(unsigned int w) {
    return __builtin_amdgcn_cvt_f32_fp8(w, SEL);   // OCP e4m3 on gfx950
}

// ---- prep: x (f32) -> xb (fp8 e4m3), 4 elems/thread ----
__global__ void k_prep_x(const float* __restrict__ x, unsigned int* __restrict__ xb) {
    int i = blockIdx.x * 256 + threadIdx.x;
    if (i >= NNODE * CIN / 4) return;
    float4 v = *reinterpret_cast<const float4*>(x + (size_t)i * 4);
    int p = __builtin_amdgcn_cvt_pk_fp8_f32(v.x, v.y, 0, false);
    p = __builtin_amdgcn_cvt_pk_fp8_f32(v.z, v.w, p, true);
    xb[i] = (unsigned int)p;
}

// ---- prep: blocks [0,391): per-node counting sort by type + boundary mask;
//            blocks [391,407): W (f32 [8][64][64]) -> B-fragment bf16, k = r*64+ki ----
__global__ void k_sort(const float* __restrict__ W,
                       const int* __restrict__ ptr, const int* __restrict__ idx,
                       const int* __restrict__ et, int* __restrict__ sidx,
                       u64* __restrict__ typ4, unsigned short* __restrict__ bm,
                       unsigned short* __restrict__ wf) {
    int b = blockIdx.x;
    if (b >= 391) {
        int tid = (b - 391) * 256 + threadIdx.x;
        if (tid >= 64 * 64) return;
        int tile = tid >> 6, lane = tid & 63;
        int kt = tile >> 2, nt = tile & 3;
        int kbase = kt * 32 + (lane >> 4) * 8;
        int col = nt * 16 + (lane & 15);
        unsigned short v[8];
#pragma unroll
        for (int j = 0; j < 8; ++j)
            v[j] = f2bf(W[(kbase + j) * 64 + col]);
        ushort4* dst = reinterpret_cast<ushort4*>(wf + (size_t)tid * 8);
        ushort4 lo, hi;
        lo.x = v[0]; lo.y = v[1]; lo.z = v[2]; lo.w = v[3];
        hi.x = v[4]; hi.y = v[5]; hi.z = v[6]; hi.w = v[7];
        dst[0] = lo; dst[1] = hi;
        return;
    }
    int node = b * 256 + threadIdx.x;
    if (node >= NNODE) return;
    int eb = ptr[node], en = ptr[node + 1];
    if (en - eb != 16) { typ4[node] = 0; bm[node] = 0; return; }
    u64 cnt = 0;
#pragma unroll
    for (int ee = 0; ee < 16; ++ee)
        cnt += 1ull << (8 * et[eb + ee]);
    u64 pre = cnt * 0x0101010101010100ull;   // exclusive byte prefix sums
    u64 occ = 0, tp = 0;
#pragma unroll
    for (int ee = 0; ee < 16; ++ee) {
        int te = et[eb + ee];
        int sh = te * 8;
        int pos = (int)((pre >> sh) & 0xFF) + (int)((occ >> sh) & 0xFF);
        occ += 1ull << sh;
        sidx[eb + pos] = idx[eb + ee];
        tp |= (u64)te << (4 * pos);
    }
    typ4[node] = tp;
    // boundary mask: bit ee = 1 iff sorted run ends at position ee
    unsigned int m = 0;
#pragma unroll
    for (int ee = 0; ee < 15; ++ee) {
        int a = (int)((tp >> (4 * ee)) & 0xF);
        int c = (int)((tp >> (4 * ee + 4)) & 0xF);
        if (a != c) m |= (1u << ee);
    }
    m |= (1u << 15);
    bm[node] = (unsigned short)m;
}

// ---- main: R13 structure + boundary-mask flush test ----
__launch_bounds__(256, 8)
__global__ void k_main(const unsigned char* __restrict__ xb,
                       const bf16x8* __restrict__ wf,
                       const int* __restrict__ ptr,
                       const int* __restrict__ sidx,
                       const u64* __restrict__ typ4,
                       const unsigned short* __restrict__ bm,
                       const int* __restrict__ idx,
                       const int* __restrict__ et,
                       const int* __restrict__ hmap,
                       const float* __restrict__ hbuf,
                       float* __restrict__ out) {
    __shared__ __align__(16) unsigned short S[8192];   // 16 rows x 512 k, 16 KB
    __shared__ __align__(16) int VS[4][64];            // per-wave sorted-source strip

    int wave = __builtin_amdgcn_readfirstlane((int)(threadIdx.x >> 6));
    int lane = threadIdx.x & 63;
    int n0 = blockIdx.x * 16;
    int nbase = n0 + wave * 4;
    char* sb = reinterpret_cast<char*>(&S[0]);

    {
        f32x4 z = {0.f, 0.f, 0.f, 0.f};
        f32x4* sz = reinterpret_cast<f32x4*>(sb);
        sz[threadIdx.x]       = z;
        sz[threadIdx.x + 256] = z;
        sz[threadIdx.x + 512] = z;
        sz[threadIdx.x + 768] = z;
    }
    __syncthreads();

    int ebX = nbase * 16;
    int eb0 = ptr[nbase + 0], eb1 = ptr[nbase + 1], eb2 = ptr[nbase + 2],
        eb3 = ptr[nbase + 3], eb4 = ptr[nbase + 4];
    bool fixed16 = (eb0 == ebX) && (eb1 == ebX + 16) && (eb2 == ebX + 32) &&
                   (eb3 == ebX + 48) && (eb4 == ebX + 64);

    if (fixed16) {
        VS[wave][lane] = sidx[ebX + lane];

        u64 tp0 = typ4[nbase + 0], tp1 = typ4[nbase + 1],
            tp2 = typ4[nbase + 2], tp3 = typ4[nbase + 3];
        u64 bm4 = *reinterpret_cast<const u64*>(bm + nbase);   // 4x u16, aligned

        int g = lane >> 4;
        u64 tpg = (g == 0) ? tp0 : ((g == 1) ? tp1 : ((g == 2) ? tp2 : tp3));
        unsigned int bmg = (unsigned int)((bm4 >> (16 * g)) & 0xFFFFull);
        int row = wave * 4 + g;
        unsigned int rowxor  = ((unsigned int)(row & 7)) << 4;
        unsigned int rowbase = (unsigned int)row * 1024u;
        unsigned int chb     = (unsigned int)(lane & 15) * 8u;
        unsigned int choff   = (unsigned int)(lane & 15) * 4u;

        const int* vsp = &VS[wave][g * 16];
        int4 q0 = *reinterpret_cast<const int4*>(vsp);
        int4 q1 = *reinterpret_cast<const int4*>(vsp + 4);
        int4 q2 = *reinterpret_cast<const int4*>(vsp + 8);
        int4 q3 = *reinterpret_cast<const int4*>(vsp + 12);

#define LD(s) (*reinterpret_cast<const unsigned int*>( \
                   xb + (size_t)(((unsigned int)(s)) * 64u + choff)))
        unsigned int d0  = LD(q0.x), d1  = LD(q0.y), d2  = LD(q0.z), d3  = LD(q0.w);
        unsigned int d4  = LD(q1.x), d5  = LD(q1.y), d6  = LD(q1.z), d7  = LD(q1.w);
        unsigned int d8  = LD(q2.x), d9  = LD(q2.y), d10 = LD(q2.z), d11 = LD(q2.w);
        unsigned int d12 = LD(q3.x), d13 = LD(q3.y), d14 = LD(q3.z), d15 = LD(q3.w);
#undef LD

        float s0 = 0.f, s1 = 0.f, s2 = 0.f, s3 = 0.f;

#define STEP(ee, dd)                                                          \
        {                                                                     \
            f32x2 plo = __builtin_amdgcn_cvt_pk_f32_fp8((int)(dd), false);    \
            f32x2 phi = __builtin_amdgcn_cvt_pk_f32_fp8((int)(dd), true);     \
            s0 += plo[0]; s1 += plo[1]; s2 += phi[0]; s3 += phi[1];           \
            if ((bmg >> (ee)) & 1u) {                                         \
                int tcur = (int)((tpg >> ((4 * (ee)) & 63)) & 0xF);           \
                unsigned int lo = (unsigned int)f2bf(s0)                      \
                                | ((unsigned int)f2bf(s1) << 16);             \
                unsigned int hi = (unsigned int)f2bf(s2)                      \
                                | ((unsigned int)f2bf(s3) << 16);             \
                unsigned int byte = (rowbase + (unsigned int)tcur * 128u + chb) \
                                    ^ rowxor;                                 \
                uint2 pk; pk.x = lo; pk.y = hi;                               \
                *reinterpret_cast<uint2*>(sb + byte) = pk;                    \
                s0 = 0.f; s1 = 0.f; s2 = 0.f; s3 = 0.f;                       \
            }                                                                 \
        }

        STEP(0, d0);   STEP(1, d1);   STEP(2, d2);   STEP(3, d3);
        STEP(4, d4);   STEP(5, d5);   STEP(6, d6);   STEP(7, d7);
        STEP(8, d8);   STEP(9, d9);   STEP(10, d10); STEP(11, d11);
        STEP(12, d12); STEP(13, d13); STEP(14, d14); STEP(15, d15);
#undef STEP
    } else {
        int l16 = lane & 15;
        int ebs[5] = {eb0, eb1, eb2, eb3, eb4};
        for (int nn = 0; nn < 4; ++nn) {
            int eb = ebs[nn], en = ebs[nn + 1];
            float s0=0.f,s1=0.f,s2=0.f,s3=0.f,s4=0.f,s5=0.f,s6=0.f,s7=0.f;
            for (int e = eb; e < en; e += 16) {
                int m = en - e; if (m > 16) m = 16;
                int vi = 0, vt = 0;
                if (l16 < m) { vi = idx[e + l16]; vt = et[e + l16]; }
                for (int ee = 0; ee < m; ++ee) {
                    int src = __builtin_amdgcn_readlane(vi, ee);
                    int t   = __builtin_amdgcn_readlane(vt, ee);
                    float v = f8tof<0>((unsigned int)xb[(size_t)(unsigned)src * 64 + lane]);
                    if      (t == 0) s0 += v;
                    else if (t == 1) s1 += v;
                    else if (t == 2) s2 += v;
                    else if (t == 3) s3 += v;
                    else if (t == 4) s4 += v;
                    else if (t == 5) s5 += v;
                    else if (t == 6) s6 += v;
                    else             s7 += v;
                }
            }
            int row = wave * 4 + nn;
            unsigned int vlx = ((unsigned int)lane * 2u)
                               ^ (((unsigned int)(row & 7)) << 4);
            unsigned int rb = (unsigned int)row * 1024u;
            float sv[8] = {s0,s1,s2,s3,s4,s5,s6,s7};
#pragma unroll
            for (int r = 0; r < 8; ++r) {
                unsigned int byte = rb + (unsigned int)r * 128u + vlx;
                *reinterpret_cast<unsigned short*>(sb + byte) = f2bf(sv[r]);
            }
        }
    }
    __syncthreads();

    // ---------- MFMA phase: wave handles N-slice nt = wave ----------
    int nt = wave;
    f32x4 acc = {0.f,0.f,0.f,0.f};
    unsigned int arow  = (unsigned int)(lane & 15);
    unsigned int abase = arow * 1024u + (unsigned int)((lane >> 4) * 16);
    unsigned int axor  = (arow & 7u) << 4;
#pragma unroll 4
    for (int kt = 0; kt < 16; ++kt) {
        unsigned int abyte = (abase + (unsigned int)kt * 64u) ^ axor;
        bf16x8 a = *reinterpret_cast<const bf16x8*>(sb + abyte);
        bf16x8 b = wf[(kt * 4 + nt) * 64 + lane];
        acc = __builtin_amdgcn_mfma_f32_16x16x32_bf16(a, b, acc, 0, 0, 0);
    }

    // ---------- epilogue: /deg, history overwrite, write both outputs ----------
    int col   = nt * 16 + (lane & 15);
    int rquad = (lane >> 4) * 4;
#pragma unroll
    for (int j = 0; j < 4; ++j) {
        int node = n0 + rquad + j;
        float invd = 1.0f / (float)(ptr[node + 1] - ptr[node]);
        float v = acc[j] * invd;
        if (hmap[node] != -1) v = hbuf[node * 64 + col];
        out[node * 64 + col] = v;
        out[NNODE * 64 + node * 64 + col] = v;
    }
}

extern "C" void kernel_launch(void* const* d_in, const int* in_sizes, int n_in,
                              void* d_out, int out_size, void* d_ws, size_t ws_size,
                              hipStream_t stream) {
    (void)in_sizes; (void)n_in; (void)out_size; (void)ws_size;
    const float* x    = (const float*)d_in[0];
    const float* W    = (const float*)d_in[1];
    const int*   ptr  = (const int*)d_in[2];
    const int*   idx  = (const int*)d_in[3];
    const int*   et   = (const int*)d_in[4];
    const int*   hmap = (const int*)d_in[6];
    const float* hbuf = (const float*)d_in[7];
    float* out = (float*)d_out;

    // workspace: xb(fp8) 6.4MB | wf 64KB | sidx 6.4MB | typ4 800KB | bm 200KB
    char* w = (char*)d_ws;
    unsigned char*  xb  = (unsigned char*)w;                   //  6,400,000 B
    unsigned short* wfu = (unsigned short*)(w + 6400000);      //     65,536 B
    int*            sidx= (int*)(w + 6465536);                 //  6,400,000 B
    u64*            tp4 = (u64*)(w + 12865536);                //    800,000 B
    unsigned short* bm  = (unsigned short*)(w + 13665536);     //    200,000 B

    k_prep_x<<<dim3(6250), dim3(256), 0, stream>>>(x, (unsigned int*)xb);
    k_sort<<<dim3(391 + 16), dim3(256), 0, stream>>>(W, ptr, idx, et, sidx, tp4, bm, wfu);
    k_main<<<dim3(NGRP), dim3(256), 0, stream>>>(
        xb, (const bf16x8*)wfu, ptr, sidx, tp4, bm, idx, et, hmap, hbuf, out);
}

// Round 17
// 63.428 us; speedup vs baseline: 1.7753x; 1.0019x over previous
//
#include <hip/hip_runtime.h>
#include <hip/hip_bf16.h>

#define NNODE 100000
#define CIN   64
#define CHID  64
#define NREL  8
#define NGRP  6250     // NNODE / 16

typedef __attribute__((ext_vector_type(8))) short bf16x8;
typedef __attribute__((ext_vector_type(4))) float f32x4;
typedef __attribute__((ext_vector_type(2))) float f32x2;
typedef unsigned long long u64;

__device__ __forceinline__ unsigned short f2bf(float f) {
    __hip_bfloat16 h = __float2bfloat16(f);
    return __builtin_bit_cast(unsigned short, h);
}
template <int SEL>
__device__ __forceinline__ float f8tof(unsigned int w) {
    return __builtin_amdgcn_cvt_f32_fp8(w, SEL);   // OCP e4m3 on gfx950
}

// ---- prep: x (f32) -> xb (fp8 e4m3), 4 elems/thread ----
__global__ void k_prep_x(const float* __restrict__ x, unsigned int* __restrict__ xb) {
    int i = blockIdx.x * 256 + threadIdx.x;
    if (i >= NNODE * CIN / 4) return;
    float4 v = *reinterpret_cast<const float4*>(x + (size_t)i * 4);
    int p = __builtin_amdgcn_cvt_pk_fp8_f32(v.x, v.y, 0, false);
    p = __builtin_amdgcn_cvt_pk_fp8_f32(v.z, v.w, p, true);
    xb[i] = (unsigned int)p;
}

// ---- prep: blocks [0,391): per-node counting sort by type + boundary mask;
//            blocks [391,407): W (f32 [8][64][64]) -> B-fragment bf16, k = r*64+ki ----
__global__ void k_sort(const float* __restrict__ W,
                       const int* __restrict__ ptr, const int* __restrict__ idx,
                       const int* __restrict__ et, int* __restrict__ sidx,
                       u64* __restrict__ typ4, unsigned short* __restrict__ bm,
                       unsigned short* __restrict__ wf) {
    int b = blockIdx.x;
    if (b >= 391) {
        int tid = (b - 391) * 256 + threadIdx.x;
        if (tid >= 64 * 64) return;
        int tile = tid >> 6, lane = tid & 63;
        int kt = tile >> 2, nt = tile & 3;
        int kbase = kt * 32 + (lane >> 4) * 8;
        int col = nt * 16 + (lane & 15);
        unsigned short v[8];
#pragma unroll
        for (int j = 0; j < 8; ++j)
            v[j] = f2bf(W[(kbase + j) * 64 + col]);
        ushort4* dst = reinterpret_cast<ushort4*>(wf + (size_t)tid * 8);
        ushort4 lo, hi;
        lo.x = v[0]; lo.y = v[1]; lo.z = v[2]; lo.w = v[3];
        hi.x = v[4]; hi.y = v[5]; hi.z = v[6]; hi.w = v[7];
        dst[0] = lo; dst[1] = hi;
        return;
    }
    int node = b * 256 + threadIdx.x;
    if (node >= NNODE) return;
    int eb = ptr[node], en = ptr[node + 1];
    if (en - eb != 16) { typ4[node] = 0; bm[node] = 0; return; }
    u64 cnt = 0;
#pragma unroll
    for (int ee = 0; ee < 16; ++ee)
        cnt += 1ull << (8 * et[eb + ee]);
    u64 pre = cnt * 0x0101010101010100ull;   // exclusive byte prefix sums
    u64 occ = 0, tp = 0;
#pragma unroll
    for (int ee = 0; ee < 16; ++ee) {
        int te = et[eb + ee];
        int sh = te * 8;
        int pos = (int)((pre >> sh) & 0xFF) + (int)((occ >> sh) & 0xFF);
        occ += 1ull << sh;
        sidx[eb + pos] = idx[eb + ee];
        tp |= (u64)te << (4 * pos);
    }
    typ4[node] = tp;
    // boundary mask: bit ee = 1 iff sorted run ends at position ee
    unsigned int m = 0;
#pragma unroll
    for (int ee = 0; ee < 15; ++ee) {
        int a = (int)((tp >> (4 * ee)) & 0xF);
        int c = (int)((tp >> (4 * ee + 4)) & 0xF);
        if (a != c) m |= (1u << ee);
    }
    m |= (1u << 15);
    bm[node] = (unsigned short)m;
}

// ---- main: R16 structure; STEP accumulates via f32x2 packed adds ----
__launch_bounds__(256, 8)
__global__ void k_main(const unsigned char* __restrict__ xb,
                       const bf16x8* __restrict__ wf,
                       const int* __restrict__ ptr,
                       const int* __restrict__ sidx,
                       const u64* __restrict__ typ4,
                       const unsigned short* __restrict__ bm,
                       const int* __restrict__ idx,
                       const int* __restrict__ et,
                       const int* __restrict__ hmap,
                       const float* __restrict__ hbuf,
                       float* __restrict__ out) {
    __shared__ __align__(16) unsigned short S[8192];   // 16 rows x 512 k, 16 KB
    __shared__ __align__(16) int VS[4][64];            // per-wave sorted-source strip

    int wave = __builtin_amdgcn_readfirstlane((int)(threadIdx.x >> 6));
    int lane = threadIdx.x & 63;
    int n0 = blockIdx.x * 16;
    int nbase = n0 + wave * 4;
    char* sb = reinterpret_cast<char*>(&S[0]);

    {
        f32x4 z = {0.f, 0.f, 0.f, 0.f};
        f32x4* sz = reinterpret_cast<f32x4*>(sb);
        sz[threadIdx.x]       = z;
        sz[threadIdx.x + 256] = z;
        sz[threadIdx.x + 512] = z;
        sz[threadIdx.x + 768] = z;
    }
    __syncthreads();

    int ebX = nbase * 16;
    int eb0 = ptr[nbase + 0], eb1 = ptr[nbase + 1], eb2 = ptr[nbase + 2],
        eb3 = ptr[nbase + 3], eb4 = ptr[nbase + 4];
    bool fixed16 = (eb0 == ebX) && (eb1 == ebX + 16) && (eb2 == ebX + 32) &&
                   (eb3 == ebX + 48) && (eb4 == ebX + 64);

    if (fixed16) {
        VS[wave][lane] = sidx[ebX + lane];

        u64 tp0 = typ4[nbase + 0], tp1 = typ4[nbase + 1],
            tp2 = typ4[nbase + 2], tp3 = typ4[nbase + 3];
        u64 bm4 = *reinterpret_cast<const u64*>(bm + nbase);   // 4x u16, aligned

        int g = lane >> 4;
        u64 tpg = (g == 0) ? tp0 : ((g == 1) ? tp1 : ((g == 2) ? tp2 : tp3));
        unsigned int bmg = (unsigned int)((bm4 >> (16 * g)) & 0xFFFFull);
        int row = wave * 4 + g;
        unsigned int rowxor  = ((unsigned int)(row & 7)) << 4;
        unsigned int rowbase = (unsigned int)row * 1024u;
        unsigned int chb     = (unsigned int)(lane & 15) * 8u;
        unsigned int choff   = (unsigned int)(lane & 15) * 4u;

        const int* vsp = &VS[wave][g * 16];
        int4 q0 = *reinterpret_cast<const int4*>(vsp);
        int4 q1 = *reinterpret_cast<const int4*>(vsp + 4);
        int4 q2 = *reinterpret_cast<const int4*>(vsp + 8);
        int4 q3 = *reinterpret_cast<const int4*>(vsp + 12);

#define LD(s) (*reinterpret_cast<const unsigned int*>( \
                   xb + (size_t)(((unsigned int)(s)) * 64u + choff)))
        unsigned int d0  = LD(q0.x), d1  = LD(q0.y), d2  = LD(q0.z), d3  = LD(q0.w);
        unsigned int d4  = LD(q1.x), d5  = LD(q1.y), d6  = LD(q1.z), d7  = LD(q1.w);
        unsigned int d8  = LD(q2.x), d9  = LD(q2.y), d10 = LD(q2.z), d11 = LD(q2.w);
        unsigned int d12 = LD(q3.x), d13 = LD(q3.y), d14 = LD(q3.z), d15 = LD(q3.w);
#undef LD

        f32x2 sA = {0.f, 0.f}, sB = {0.f, 0.f};

#define STEP(ee, dd)                                                          \
        {                                                                     \
            sA += __builtin_amdgcn_cvt_pk_f32_fp8((int)(dd), false);          \
            sB += __builtin_amdgcn_cvt_pk_f32_fp8((int)(dd), true);           \
            if ((bmg >> (ee)) & 1u) {                                         \
                int tcur = (int)((tpg >> ((4 * (ee)) & 63)) & 0xF);           \
                unsigned int lo = (unsigned int)f2bf(sA[0])                   \
                                | ((unsigned int)f2bf(sA[1]) << 16);          \
                unsigned int hi = (unsigned int)f2bf(sB[0])                   \
                                | ((unsigned int)f2bf(sB[1]) << 16);          \
                unsigned int byte = (rowbase + (unsigned int)tcur * 128u + chb) \
                                    ^ rowxor;                                 \
                uint2 pk; pk.x = lo; pk.y = hi;                               \
                *reinterpret_cast<uint2*>(sb + byte) = pk;                    \
                sA[0] = 0.f; sA[1] = 0.f; sB[0] = 0.f; sB[1] = 0.f;           \
            }                                                                 \
        }

        STEP(0, d0);   STEP(1, d1);   STEP(2, d2);   STEP(3, d3);
        STEP(4, d4);   STEP(5, d5);   STEP(6, d6);   STEP(7, d7);
        STEP(8, d8);   STEP(9, d9);   STEP(10, d10); STEP(11, d11);
        STEP(12, d12); STEP(13, d13); STEP(14, d14); STEP(15, d15);
#undef STEP
    } else {
        int l16 = lane & 15;
        int ebs[5] = {eb0, eb1, eb2, eb3, eb4};
        for (int nn = 0; nn < 4; ++nn) {
            int eb = ebs[nn], en = ebs[nn + 1];
            float s0=0.f,s1=0.f,s2=0.f,s3=0.f,s4=0.f,s5=0.f,s6=0.f,s7=0.f;
            for (int e = eb; e < en; e += 16) {
                int m = en - e; if (m > 16) m = 16;
                int vi = 0, vt = 0;
                if (l16 < m) { vi = idx[e + l16]; vt = et[e + l16]; }
                for (int ee = 0; ee < m; ++ee) {
                    int src = __builtin_amdgcn_readlane(vi, ee);
                    int t   = __builtin_amdgcn_readlane(vt, ee);
                    float v = f8tof<0>((unsigned int)xb[(size_t)(unsigned)src * 64 + lane]);
                    if      (t == 0) s0 += v;
                    else if (t == 1) s1 += v;
                    else if (t == 2) s2 += v;
                    else if (t == 3) s3 += v;
                    else if (t == 4) s4 += v;
                    else if (t == 5) s5 += v;
                    else if (t == 6) s6 += v;
                    else             s7 += v;
                }
            }
            int row = wave * 4 + nn;
            unsigned int vlx = ((unsigned int)lane * 2u)
                               ^ (((unsigned int)(row & 7)) << 4);
            unsigned int rb = (unsigned int)row * 1024u;
            float sv[8] = {s0,s1,s2,s3,s4,s5,s6,s7};
#pragma unroll
            for (int r = 0; r < 8; ++r) {
                unsigned int byte = rb + (unsigned int)r * 128u + vlx;
                *reinterpret_cast<unsigned short*>(sb + byte) = f2bf(sv[r]);
            }
        }
    }
    __syncthreads();

    // ---------- MFMA phase: wave handles N-slice nt = wave ----------
    int nt = wave;
    f32x4 acc = {0.f,0.f,0.f,0.f};
    unsigned int arow  = (unsigned int)(lane & 15);
    unsigned int abase = arow * 1024u + (unsigned int)((lane >> 4) * 16);
    unsigned int axor  = (arow & 7u) << 4;
#pragma unroll 4
    for (int kt = 0; kt < 16; ++kt) {
        unsigned int abyte = (abase + (unsigned int)kt * 64u) ^ axor;
        bf16x8 a = *reinterpret_cast<const bf16x8*>(sb + abyte);
        bf16x8 b = wf[(kt * 4 + nt) * 64 + lane];
        acc = __builtin_amdgcn_mfma_f32_16x16x32_bf16(a, b, acc, 0, 0, 0);
    }

    // ---------- epilogue: /deg, history overwrite, write both outputs ----------
    int col   = nt * 16 + (lane & 15);
    int rquad = (lane >> 4) * 4;
#pragma unroll
    for (int j = 0; j < 4; ++j) {
        int node = n0 + rquad + j;
        float invd = 1.0f / (float)(ptr[node + 1] - ptr[node]);
        float v = acc[j] * invd;
        if (hmap[node] != -1) v = hbuf[node * 64 + col];
        out[node * 64 + col] = v;
        out[NNODE * 64 + node * 64 + col] = v;
    }
}

extern "C" void kernel_launch(void* const* d_in, const int* in_sizes, int n_in,
                              void* d_out, int out_size, void* d_ws, size_t ws_size,
                              hipStream_t stream) {
    (void)in_sizes; (void)n_in; (void)out_size; (void)ws_size;
    const float* x    = (const float*)d_in[0];
    const float* W    = (const float*)d_in[1];
    const int*   ptr  = (const int*)d_in[2];
    const int*   idx  = (const int*)d_in[3];
    const int*   et   = (const int*)d_in[4];
    const int*   hmap = (const int*)d_in[6];
    const float* hbuf = (const float*)d_in[7];
    float* out = (float*)d_out;

    // workspace: xb(fp8) 6.4MB | wf 64KB | sidx 6.4MB | typ4 800KB | bm 200KB
    char* w = (char*)d_ws;
    unsigned char*  xb  = (unsigned char*)w;                   //  6,400,000 B
    unsigned short* wfu = (unsigned short*)(w + 6400000);      //     65,536 B
    int*            sidx= (int*)(w + 6465536);                 //  6,400,000 B
    u64*            tp4 = (u64*)(w + 12865536);                //    800,000 B
    unsigned short* bm  = (unsigned short*)(w + 13665536);     //    200,000 B

    k_prep_x<<<dim3(6250), dim3(256), 0, stream>>>(x, (unsigned int*)xb);
    k_sort<<<dim3(391 + 16), dim3(256), 0, stream>>>(W, ptr, idx, et, sidx, tp4, bm, wfu);
    k_main<<<dim3(NGRP), dim3(256), 0, stream>>>(
        xb, (const bf16x8*)wfu, ptr, sidx, tp4, bm, idx, et, hmap, hbuf, out);
}